// Round 4
// baseline (358.784 us; speedup 1.0000x reference)
//
#include <hip/hip_runtime.h>
#include <math.h>

// ---- Problem constants ----
#define B_    128
#define L_    512
#define H_    128
#define NPT_  1023
#define N_    (B_ * NPT_)     // 130944
#define NLEAF (B_ * L_)       // 65536
#define OUT_  128

#define PADK  264             // 256 + 8 shorts: level A-tile row stride
#define PADKL 136             // 128 + 8 shorts: leaf  A-tile row stride

typedef unsigned short ushort_t;
typedef __attribute__((ext_vector_type(8))) __bf16 bf16x8;
typedef __attribute__((ext_vector_type(4))) float f32x4;

__device__ __forceinline__ float sigmoidf_(float x) {
    return 1.0f / (1.0f + __expf(-x));
}
__device__ __forceinline__ float tanhf_(float x) {
    return 1.0f - 2.0f / (__expf(2.0f * x) + 1.0f);
}
__device__ __forceinline__ ushort_t f2bf(float f) {
    unsigned u = __float_as_uint(f);
    return (ushort_t)((u + 0x7fffu + ((u >> 16) & 1u)) >> 16);
}
__device__ __forceinline__ float bf2f(ushort_t s) {
    return __uint_as_float(((unsigned)s) << 16);
}

// =====================================================================
// Prep: cast weights to bf16, transposed. U_catT[n][k] (n<384: U_iou,
// else U_f_w), W_iouT[n][k].
// =====================================================================
__global__ __launch_bounds__(256)
void prep_kernel(const float* __restrict__ W_iou,
                 const float* __restrict__ U_iou,
                 const float* __restrict__ U_f_w,
                 ushort_t* __restrict__ W_iouT,     // [384][128]
                 ushort_t* __restrict__ U_catT) {   // [640][256]
    int idx = blockIdx.x * 256 + threadIdx.x;
    if (idx < 640 * 256) {
        int n = idx >> 8, k = idx & 255;
        float v = (n < 384) ? U_iou[k * 384 + n] : U_f_w[k * 256 + (n - 384)];
        U_catT[idx] = f2bf(v);
    }
    if (idx < 384 * 128) {
        int n = idx >> 7, k = idx & 127;
        W_iouT[idx] = f2bf(W_iou[k * 384 + n]);
    }
}

// =====================================================================
// Leaf: block = 4 waves, M-tile = 64 leaves staged in LDS (bf16, padded).
// Wave w handles gate group gg = 4*blockIdx.y + w over all M=64.
// Tiles {gg, gg+8, gg+16} = (i,o,u) -> lane-local cell epilogue.
// =====================================================================
__global__ __launch_bounds__(256)
void leaf_mfma(const int* __restrict__ label,
               const float* __restrict__ emb,
               const ushort_t* __restrict__ WT,     // [384][128] bf16
               const float* __restrict__ b_iou,
               ushort_t* __restrict__ h,
               float* __restrict__ c) {
    __shared__ ushort_t As[64 * PADKL];             // 17.4 KB
    const int tid  = threadIdx.x;
    const int lane = tid & 63;
    const int wave = tid >> 6;
    const int li   = lane & 15;
    const int q    = lane >> 4;
    const int q8   = q << 3;
    const int i0   = blockIdx.x * 64;
    const int gg   = blockIdx.y * 4 + wave;

    // stage A: 64 emb rows (gather via label), f32 -> bf16, into LDS
    {
        int r  = tid >> 2;          // leaf-row 0..63
        int qq = tid & 3;           // 32-col quarter
        int i  = i0 + r;
        int b  = i >> 9, pos = i & 511;
        const float* src = emb + (size_t)label[b * NPT_ + pos] * H_ + qq * 32;
        ushort_t*    dst = As + r * PADKL + qq * 32;
        #pragma unroll
        for (int u = 0; u < 4; ++u) {
            f32x4 f0 = *(const f32x4*)(src + u * 8);
            f32x4 f1 = *(const f32x4*)(src + u * 8 + 4);
            union { bf16x8 v; ushort_t e[8]; } p;
            p.e[0] = f2bf(f0[0]); p.e[1] = f2bf(f0[1]);
            p.e[2] = f2bf(f0[2]); p.e[3] = f2bf(f0[3]);
            p.e[4] = f2bf(f1[0]); p.e[5] = f2bf(f1[1]);
            p.e[6] = f2bf(f1[2]); p.e[7] = f2bf(f1[3]);
            *(bf16x8*)(dst + u * 8) = p.v;
        }
    }
    __syncthreads();

    const ushort_t* bp[3];
    #pragma unroll
    for (int t = 0; t < 3; ++t)
        bp[t] = WT + (size_t)(16 * (gg + 8 * t) + li) * 128 + q8;

    f32x4 acc[4][3];
    #pragma unroll
    for (int s = 0; s < 4; ++s)
        #pragma unroll
        for (int t = 0; t < 3; ++t) acc[s][t] = (f32x4){0.f, 0.f, 0.f, 0.f};

    #pragma unroll
    for (int kt = 0; kt < 4; ++kt) {
        bf16x8 a[4];
        #pragma unroll
        for (int sub = 0; sub < 4; ++sub)
            a[sub] = *(const bf16x8*)(As + (sub * 16 + li) * PADKL + kt * 32 + q8);
        #pragma unroll
        for (int t = 0; t < 3; ++t) {
            bf16x8 bf = *(const bf16x8*)(bp[t] + kt * 32);
            #pragma unroll
            for (int sub = 0; sub < 4; ++sub)
                acc[sub][t] = __builtin_amdgcn_mfma_f32_16x16x32_bf16(a[sub], bf, acc[sub][t], 0, 0, 0);
        }
    }

    const int j = gg * 16 + li;
    const float bi = b_iou[j], bo = b_iou[128 + j], bu = b_iou[256 + j];
    #pragma unroll
    for (int sub = 0; sub < 4; ++sub) {
        #pragma unroll
        for (int r = 0; r < 4; ++r) {
            int m  = i0 + sub * 16 + q * 4 + r;     // row = 4*quad + reg
            int b  = m >> 9, pos = m & 511;
            size_t gn = (size_t)(b * NPT_ + pos) * H_ + j;
            float iv = sigmoidf_(acc[sub][0][r] + bi);
            float ov = sigmoidf_(acc[sub][1][r] + bo);
            float uv = tanhf_(acc[sub][2][r] + bu);
            float cv = iv * uv;                     // c_in = 0 at leaves
            float hv = ov * tanhf_(cv);
            c[gn] = cv;
            h[gn] = f2bf(hv);
        }
    }
}

// =====================================================================
// Level: block = 4 waves, M-tile = 64 nodes; h_cat (64x256) staged in
// LDS (padded) from the 128 child h-rows. Wave w handles gate group
// gg = 4*blockIdx.y + w over all M=64. Tiles {gg,+8,+16,+24,+32} =
// (i,o,u,fl,fr) -> lane-local epilogue with f32 c-children.
// =====================================================================
__global__ __launch_bounds__(256)
void level_mfma(const ushort_t* __restrict__ Ucat,   // [640][256] bf16
                const float* __restrict__ b_iou,
                const float* __restrict__ U_f_b,
                ushort_t* __restrict__ h,
                float* __restrict__ c,
                int node_base, int child_base, int lc) {
    __shared__ ushort_t As[64 * PADK];              // 33.8 KB
    const int tid  = threadIdx.x;
    const int lane = tid & 63;
    const int wave = tid >> 6;
    const int li   = lane & 15;
    const int q    = lane >> 4;
    const int q8   = q << 3;
    const int mask = (1 << lc) - 1;
    const int i0   = blockIdx.x * 64;
    const int gg   = blockIdx.y * 4 + wave;

    // stage A: h_cat rows; row r = [h[left(r)] | h[right(r)]]
    {
        int r  = tid >> 2;          // node-row 0..63
        int qq = tid & 3;           // side s = qq>>1, half hh = qq&1
        int s  = qq >> 1, hh = qq & 1;
        int i  = i0 + r;
        int b  = i >> lc, pos = i & mask;
        int gc = b * NPT_ + child_base + 2 * pos + s;
        const ushort_t* src = h + (size_t)gc * H_ + hh * 64;
        ushort_t*       dst = As + r * PADK + s * 128 + hh * 64;
        #pragma unroll
        for (int u = 0; u < 8; ++u)
            *(f32x4*)(dst + u * 8) = *(const f32x4*)(src + u * 8);
    }
    __syncthreads();

    const ushort_t* bp[5];
    #pragma unroll
    for (int t = 0; t < 5; ++t)
        bp[t] = Ucat + (size_t)(16 * (gg + 8 * t) + li) * 256 + q8;

    f32x4 acc[4][5];
    #pragma unroll
    for (int s = 0; s < 4; ++s)
        #pragma unroll
        for (int t = 0; t < 5; ++t) acc[s][t] = (f32x4){0.f, 0.f, 0.f, 0.f};

    #pragma unroll
    for (int kt = 0; kt < 8; ++kt) {
        bf16x8 a[4];
        #pragma unroll
        for (int sub = 0; sub < 4; ++sub)
            a[sub] = *(const bf16x8*)(As + (sub * 16 + li) * PADK + kt * 32 + q8);
        #pragma unroll
        for (int t = 0; t < 5; ++t) {
            bf16x8 bf = *(const bf16x8*)(bp[t] + kt * 32);
            #pragma unroll
            for (int sub = 0; sub < 4; ++sub)
                acc[sub][t] = __builtin_amdgcn_mfma_f32_16x16x32_bf16(a[sub], bf, acc[sub][t], 0, 0, 0);
        }
    }

    const int j = gg * 16 + li;
    const float bi  = b_iou[j], bo = b_iou[128 + j], bu = b_iou[256 + j];
    const float bfl = U_f_b[j], bfr = U_f_b[128 + j];
    #pragma unroll
    for (int sub = 0; sub < 4; ++sub) {
        #pragma unroll
        for (int r = 0; r < 4; ++r) {
            int m   = i0 + sub * 16 + q * 4 + r;    // row = 4*quad + reg
            int b   = m >> lc, pos = m & mask;
            int gn  = b * NPT_ + node_base + pos;
            int gl  = b * NPT_ + child_base + 2 * pos;
            float iv = sigmoidf_(acc[sub][0][r] + bi);
            float ov = sigmoidf_(acc[sub][1][r] + bo);
            float uv = tanhf_(acc[sub][2][r] + bu);
            float fl = sigmoidf_(acc[sub][3][r] + bfl);
            float fr = sigmoidf_(acc[sub][4][r] + bfr);
            float cv = iv * uv + fl * c[(size_t)gl * H_ + j]
                               + fr * c[(size_t)(gl + 1) * H_ + j];
            float hv = ov * tanhf_(cv);
            c[(size_t)gn * H_ + j] = cv;
            h[(size_t)gn * H_ + j] = f2bf(hv);
        }
    }
}

// =====================================================================
// Root: logits = h_root @ W_out + b_out, log_softmax. Tiny; f32 VALU.
// =====================================================================
__global__ __launch_bounds__(128)
void root_kernel(const ushort_t* __restrict__ h,
                 const float* __restrict__ W_out,
                 const float* __restrict__ b_out,
                 float* __restrict__ out) {
    __shared__ float e[H_];
    __shared__ float red[128];
    const int j = threadIdx.x;
    const int b = blockIdx.x;
    const size_t g = (size_t)(b * NPT_ + (NPT_ - 1)) * H_;

    e[j] = bf2f(h[g + j]);
    __syncthreads();

    float acc = b_out[j];
    for (int k = 0; k < H_; ++k)
        acc += e[k] * W_out[k * OUT_ + j];

    red[j] = acc; __syncthreads();
    #pragma unroll
    for (int s = 64; s > 0; s >>= 1) {
        if (j < s) red[j] = fmaxf(red[j], red[j + s]);
        __syncthreads();
    }
    float mx = red[0]; __syncthreads();

    red[j] = expf(acc - mx); __syncthreads();
    #pragma unroll
    for (int s = 64; s > 0; s >>= 1) {
        if (j < s) red[j] += red[j + s];
        __syncthreads();
    }
    float lse = logf(red[0]);

    out[b * OUT_ + j] = acc - mx - lse;
}

// =====================================================================
extern "C" void kernel_launch(void* const* d_in, const int* in_sizes, int n_in,
                              void* d_out, int out_size, void* d_ws, size_t ws_size,
                              hipStream_t stream) {
    const int*   label = (const int*)d_in[0];
    const float* emb   = (const float*)d_in[1];
    const float* W_iou = (const float*)d_in[2];
    const float* U_iou = (const float*)d_in[3];
    const float* b_iou = (const float*)d_in[4];
    const float* U_f_w = (const float*)d_in[5];
    const float* U_f_b = (const float*)d_in[6];
    const float* W_out = (const float*)d_in[7];
    const float* b_out = (const float*)d_in[8];

    // ws layout: c f32 (67 MB) | h bf16 (33.5 MB) | U_catT | W_iouT
    float*    c    = (float*)d_ws;
    ushort_t* h    = (ushort_t*)(c + (size_t)N_ * H_);
    ushort_t* Ucat = h + (size_t)N_ * H_;
    ushort_t* WT   = Ucat + 640 * 256;

    prep_kernel<<<640, 256, 0, stream>>>(W_iou, U_iou, U_f_w, WT, Ucat);

    leaf_mfma<<<dim3(NLEAF / 64, 2), 256, 0, stream>>>(label, emb, WT, b_iou, h, c);

    int child = 0, node = 512, cnt = 256, lc = 8;
    for (int lvl = 0; lvl < 9; ++lvl) {
        level_mfma<<<dim3((B_ * cnt) / 64, 2), 256, 0, stream>>>(
            Ucat, b_iou, U_f_b, h, c, node, child, lc);
        child = node; node += cnt; cnt >>= 1; --lc;
    }

    root_kernel<<<B_, 128, 0, stream>>>(h, W_out, b_out, (float*)d_out);
}

// Round 5
// 276.107 us; speedup vs baseline: 1.2994x; 1.2994x over previous
//
#include <hip/hip_runtime.h>
#include <math.h>

// ---- Problem constants ----
#define B_    128
#define L_    512
#define H_    128
#define NPT_  1023
#define N_    (B_ * NPT_)     // 130944
#define NLEAF (B_ * L_)       // 65536
#define OUT_  128
#define VOCAB 32000

#define PADK  264             // 256 + 8 shorts: level A-tile row stride (132 dw, 2-way = free)
#define PADKL 136             // 128 + 8 shorts: leaf  A-tile row stride

typedef unsigned short ushort_t;
typedef __attribute__((ext_vector_type(8))) __bf16 bf16x8;
typedef __attribute__((ext_vector_type(4))) float f32x4;

__device__ __forceinline__ float sigmoidf_(float x) {
    return 1.0f / (1.0f + __expf(-x));
}
__device__ __forceinline__ float tanhf_(float x) {
    return 1.0f - 2.0f / (__expf(2.0f * x) + 1.0f);
}
__device__ __forceinline__ ushort_t f2bf(float f) {
    unsigned u = __float_as_uint(f);
    return (ushort_t)((u + 0x7fffu + ((u >> 16) & 1u)) >> 16);
}
__device__ __forceinline__ float bf2f(ushort_t s) {
    return __uint_as_float(((unsigned)s) << 16);
}

// =====================================================================
// Prep A: weights -> bf16, transposed.
// =====================================================================
__global__ __launch_bounds__(256)
void prep_kernel(const float* __restrict__ W_iou,
                 const float* __restrict__ U_iou,
                 const float* __restrict__ U_f_w,
                 ushort_t* __restrict__ W_iouT,     // [384][128]
                 ushort_t* __restrict__ U_catT) {   // [640][256]
    int idx = blockIdx.x * 256 + threadIdx.x;
    if (idx < 640 * 256) {
        int n = idx >> 8, k = idx & 255;
        float v = (n < 384) ? U_iou[k * 384 + n] : U_f_w[k * 256 + (n - 384)];
        U_catT[idx] = f2bf(v);
    }
    if (idx < 384 * 128) {
        int n = idx >> 7, k = idx & 127;
        W_iouT[idx] = f2bf(W_iou[k * 384 + n]);
    }
}

// =====================================================================
// Prep B: emb -> bf16 (8.2 MB, L2/L3-resident; leaf staging becomes
// pure 16B copies with no VALU convert).
// =====================================================================
__global__ __launch_bounds__(256)
void prep_emb(const float* __restrict__ emb, ushort_t* __restrict__ embb) {
    int idx = (blockIdx.x * 256 + threadIdx.x) * 8;
    if (idx < VOCAB * H_) {
        f32x4 f0 = *(const f32x4*)(emb + idx);
        f32x4 f1 = *(const f32x4*)(emb + idx + 4);
        union { bf16x8 v; ushort_t e[8]; } p;
        p.e[0] = f2bf(f0[0]); p.e[1] = f2bf(f0[1]);
        p.e[2] = f2bf(f0[2]); p.e[3] = f2bf(f0[3]);
        p.e[4] = f2bf(f1[0]); p.e[5] = f2bf(f1[1]);
        p.e[6] = f2bf(f1[2]); p.e[7] = f2bf(f1[3]);
        *(bf16x8*)((ushort_t*)embb + idx) = p.v;
    }
}

// =====================================================================
// Leaf: block = 4 waves, M-tile = 32 leaves in LDS (bf16).
// Wave w -> gate group gg = blockIdx.y*4 + w, M=32 (acc[2][3]=24).
// Tiles {gg, gg+8, gg+16} = (i,o,u): lane-local cell epilogue.
// =====================================================================
__global__ __launch_bounds__(256, 4)
void leaf_mfma(const int* __restrict__ label,
               const ushort_t* __restrict__ embb,   // [VOCAB][128] bf16
               const ushort_t* __restrict__ WT,     // [384][128] bf16
               const float* __restrict__ b_iou,
               ushort_t* __restrict__ h,
               float* __restrict__ c) {
    __shared__ ushort_t As[32 * PADKL];             // 8.7 KB
    const int tid  = threadIdx.x;
    const int lane = tid & 63;
    const int wave = tid >> 6;
    const int li   = lane & 15;
    const int q    = lane >> 4;
    const int q8   = q << 3;
    const int i0   = blockIdx.x * 32;
    const int gg   = blockIdx.y * 4 + wave;

    // stage A: 32 emb_bf16 rows (gather via label)
    {
        int r   = tid >> 3;         // 0..31
        int seg = tid & 7;          // 16 shorts each
        int i   = i0 + r;
        int b   = i >> 9, pos = i & 511;
        const ushort_t* src = embb + (size_t)label[b * NPT_ + pos] * H_ + seg * 16;
        ushort_t*       dst = As + r * PADKL + seg * 16;
        *(f32x4*)(dst)     = *(const f32x4*)(src);
        *(f32x4*)(dst + 8) = *(const f32x4*)(src + 8);
    }
    __syncthreads();

    const ushort_t* bp[3];
    #pragma unroll
    for (int t = 0; t < 3; ++t)
        bp[t] = WT + (size_t)(16 * (gg + 8 * t) + li) * 128 + q8;

    f32x4 acc[2][3];
    #pragma unroll
    for (int s = 0; s < 2; ++s)
        #pragma unroll
        for (int t = 0; t < 3; ++t) acc[s][t] = (f32x4){0.f, 0.f, 0.f, 0.f};

    #pragma unroll
    for (int kt = 0; kt < 4; ++kt) {
        bf16x8 a0 = *(const bf16x8*)(As + (li) * PADKL + kt * 32 + q8);
        bf16x8 a1 = *(const bf16x8*)(As + (16 + li) * PADKL + kt * 32 + q8);
        #pragma unroll
        for (int t = 0; t < 3; ++t) {
            bf16x8 bf = *(const bf16x8*)(bp[t] + kt * 32);
            acc[0][t] = __builtin_amdgcn_mfma_f32_16x16x32_bf16(a0, bf, acc[0][t], 0, 0, 0);
            acc[1][t] = __builtin_amdgcn_mfma_f32_16x16x32_bf16(a1, bf, acc[1][t], 0, 0, 0);
        }
    }

    const int j = gg * 16 + li;
    const float bi = b_iou[j], bo = b_iou[128 + j], bu = b_iou[256 + j];
    #pragma unroll
    for (int sub = 0; sub < 2; ++sub) {
        #pragma unroll
        for (int r = 0; r < 4; ++r) {
            int m  = i0 + sub * 16 + q * 4 + r;     // row = 4*quad + reg
            int b  = m >> 9, pos = m & 511;
            size_t gn = (size_t)(b * NPT_ + pos) * H_ + j;
            float iv = sigmoidf_(acc[sub][0][r] + bi);
            float ov = sigmoidf_(acc[sub][1][r] + bo);
            float uv = tanhf_(acc[sub][2][r] + bu);
            float cv = iv * uv;                     // c_in = 0 at leaves
            float hv = ov * tanhf_(cv);
            c[gn] = cv;
            h[gn] = f2bf(hv);
        }
    }
}

// =====================================================================
// Level: block = 4 waves, M-tile = 32 nodes; h_cat (32x256) in LDS.
// Wave w -> gate group gg = blockIdx.y*4 + w, M=32 (acc[2][5]=40).
// Tiles {gg,+8,+16,+24,+32} = (i,o,u,fl,fr): lane-local epilogue.
// =====================================================================
__global__ __launch_bounds__(256, 4)
void level_mfma(const ushort_t* __restrict__ Ucat,   // [640][256] bf16
                const float* __restrict__ b_iou,
                const float* __restrict__ U_f_b,
                ushort_t* __restrict__ h,
                float* __restrict__ c,
                int node_base, int child_base, int lc) {
    __shared__ ushort_t As[32 * PADK];              // 16.9 KB
    const int tid  = threadIdx.x;
    const int lane = tid & 63;
    const int wave = tid >> 6;
    const int li   = lane & 15;
    const int q    = lane >> 4;
    const int q8   = q << 3;
    const int mask = (1 << lc) - 1;
    const int i0   = blockIdx.x * 32;
    const int gg   = blockIdx.y * 4 + wave;

    // stage A: row r = [h[left(r)] | h[right(r)]]
    {
        int r   = tid >> 3;         // 0..31
        int seg = tid & 7;          // 32 shorts each
        int s   = seg >> 2, cs = seg & 3;
        int i   = i0 + r;
        int b   = i >> lc, pos = i & mask;
        int gc  = b * NPT_ + child_base + 2 * pos + s;
        const ushort_t* src = h + (size_t)gc * H_ + cs * 32;
        ushort_t*       dst = As + r * PADK + s * 128 + cs * 32;
        #pragma unroll
        for (int u = 0; u < 4; ++u)
            *(f32x4*)(dst + u * 8) = *(const f32x4*)(src + u * 8);
    }
    __syncthreads();

    const ushort_t* bp[5];
    #pragma unroll
    for (int t = 0; t < 5; ++t)
        bp[t] = Ucat + (size_t)(16 * (gg + 8 * t) + li) * 256 + q8;

    f32x4 acc[2][5];
    #pragma unroll
    for (int s = 0; s < 2; ++s)
        #pragma unroll
        for (int t = 0; t < 5; ++t) acc[s][t] = (f32x4){0.f, 0.f, 0.f, 0.f};

    #pragma unroll
    for (int kt = 0; kt < 8; ++kt) {
        bf16x8 a0 = *(const bf16x8*)(As + (li) * PADK + kt * 32 + q8);
        bf16x8 a1 = *(const bf16x8*)(As + (16 + li) * PADK + kt * 32 + q8);
        #pragma unroll
        for (int t = 0; t < 5; ++t) {
            bf16x8 bf = *(const bf16x8*)(bp[t] + kt * 32);
            acc[0][t] = __builtin_amdgcn_mfma_f32_16x16x32_bf16(a0, bf, acc[0][t], 0, 0, 0);
            acc[1][t] = __builtin_amdgcn_mfma_f32_16x16x32_bf16(a1, bf, acc[1][t], 0, 0, 0);
        }
    }

    const int j = gg * 16 + li;
    const float bi  = b_iou[j], bo = b_iou[128 + j], bu = b_iou[256 + j];
    const float bfl = U_f_b[j], bfr = U_f_b[128 + j];
    #pragma unroll
    for (int sub = 0; sub < 2; ++sub) {
        #pragma unroll
        for (int r = 0; r < 4; ++r) {
            int m   = i0 + sub * 16 + q * 4 + r;    // row = 4*quad + reg
            int b   = m >> lc, pos = m & mask;
            int gn  = b * NPT_ + node_base + pos;
            int gl  = b * NPT_ + child_base + 2 * pos;
            float iv = sigmoidf_(acc[sub][0][r] + bi);
            float ov = sigmoidf_(acc[sub][1][r] + bo);
            float uv = tanhf_(acc[sub][2][r] + bu);
            float fl = sigmoidf_(acc[sub][3][r] + bfl);
            float fr = sigmoidf_(acc[sub][4][r] + bfr);
            float cv = iv * uv + fl * c[(size_t)gl * H_ + j]
                               + fr * c[(size_t)(gl + 1) * H_ + j];
            float hv = ov * tanhf_(cv);
            c[(size_t)gn * H_ + j] = cv;
            h[(size_t)gn * H_ + j] = f2bf(hv);
        }
    }
}

// =====================================================================
// Root: logits = h_root @ W_out + b_out, log_softmax. Tiny; f32 VALU.
// =====================================================================
__global__ __launch_bounds__(128)
void root_kernel(const ushort_t* __restrict__ h,
                 const float* __restrict__ W_out,
                 const float* __restrict__ b_out,
                 float* __restrict__ out) {
    __shared__ float e[H_];
    __shared__ float red[128];
    const int j = threadIdx.x;
    const int b = blockIdx.x;
    const size_t g = (size_t)(b * NPT_ + (NPT_ - 1)) * H_;

    e[j] = bf2f(h[g + j]);
    __syncthreads();

    float acc = b_out[j];
    for (int k = 0; k < H_; ++k)
        acc += e[k] * W_out[k * OUT_ + j];

    red[j] = acc; __syncthreads();
    #pragma unroll
    for (int s = 64; s > 0; s >>= 1) {
        if (j < s) red[j] = fmaxf(red[j], red[j + s]);
        __syncthreads();
    }
    float mx = red[0]; __syncthreads();

    red[j] = expf(acc - mx); __syncthreads();
    #pragma unroll
    for (int s = 64; s > 0; s >>= 1) {
        if (j < s) red[j] += red[j + s];
        __syncthreads();
    }
    float lse = logf(red[0]);

    out[b * OUT_ + j] = acc - mx - lse;
}

// =====================================================================
extern "C" void kernel_launch(void* const* d_in, const int* in_sizes, int n_in,
                              void* d_out, int out_size, void* d_ws, size_t ws_size,
                              hipStream_t stream) {
    const int*   label = (const int*)d_in[0];
    const float* emb   = (const float*)d_in[1];
    const float* W_iou = (const float*)d_in[2];
    const float* U_iou = (const float*)d_in[3];
    const float* b_iou = (const float*)d_in[4];
    const float* U_f_w = (const float*)d_in[5];
    const float* U_f_b = (const float*)d_in[6];
    const float* W_out = (const float*)d_in[7];
    const float* b_out = (const float*)d_in[8];

    // ws layout: c f32 (67MB) | h bf16 (33.5MB) | U_catT | W_iouT | emb_bf16
    float*    c    = (float*)d_ws;
    ushort_t* h    = (ushort_t*)(c + (size_t)N_ * H_);
    ushort_t* Ucat = h + (size_t)N_ * H_;
    ushort_t* WT   = Ucat + 640 * 256;
    ushort_t* embb = WT + 384 * 128;

    prep_kernel<<<640, 256, 0, stream>>>(W_iou, U_iou, U_f_w, WT, Ucat);
    prep_emb<<<(VOCAB * H_ / 8 + 255) / 256, 256, 0, stream>>>(emb, embb);

    leaf_mfma<<<dim3(NLEAF / 32, 2), 256, 0, stream>>>(label, embb, WT, b_iou, h, c);

    int child = 0, node = 512, cnt = 256, lc = 8;
    for (int lvl = 0; lvl < 9; ++lvl) {
        level_mfma<<<dim3((B_ * cnt) / 32, 2), 256, 0, stream>>>(
            Ucat, b_iou, U_f_b, h, c, node, child, lc);
        child = node; node += cnt; cnt >>= 1; --lc;
    }

    root_kernel<<<B_, 128, 0, stream>>>(h, W_out, b_out, (float*)d_out);
}